// Round 2
// baseline (237.617 us; speedup 1.0000x reference)
//
#include <hip/hip_runtime.h>
#include <math.h>

typedef __bf16 bf16;
typedef bf16 bf16x4 __attribute__((ext_vector_type(4)));
typedef bf16 bf16x8 __attribute__((ext_vector_type(8)));
typedef float f32x4 __attribute__((ext_vector_type(4)));

static_assert(sizeof(bf16x8) == 16, "bf16x8 must be 16B");

// q pre-scale: (1/sqrt(hd=32)) * log2(e)  -> softmax via exp2
#define QSCALE (0.17677669529663687f * 1.4426950408889634f)

__device__ __forceinline__ f32x4 mfma16(bf16x8 a, bf16x8 b, f32x4 c) {
  return __builtin_amdgcn_mfma_f32_16x16x32_bf16(a, b, c, 0, 0, 0);
}

// ---------------------------------------------------------------------------
// 0) weight prep: Wq->bf16, Wkv->bf16, w7 -> transposed fp32 w7t[tap][c]
//    grid = 32 (Wq) + 64 (Wkv) + 1 (w7t) = 97 blocks
// ---------------------------------------------------------------------------
__global__ __launch_bounds__(256) void k_cvt(
    const float* __restrict__ Wq, const float* __restrict__ Wkv,
    const float* __restrict__ w7, bf16* __restrict__ Wqb,
    bf16* __restrict__ Wkvb, float* __restrict__ w7t) {
  const int tid = threadIdx.x;
  const int blk = blockIdx.x;
  if (blk < 96) {
    const float* src;
    bf16* dst;
    if (blk < 32) {
      const int idx = blk * 256 + tid;            // Wq: 65536/8 = 8192
      src = Wq + (size_t)idx * 8;
      dst = Wqb + (size_t)idx * 8;
    } else {
      const int idx = (blk - 32) * 256 + tid;     // Wkv: 131072/8 = 16384
      src = Wkv + (size_t)idx * 8;
      dst = Wkvb + (size_t)idx * 8;
    }
    const float4 a = ((const float4*)src)[0];
    const float4 b = ((const float4*)src)[1];
    bf16x8 r;
    r[0] = (bf16)a.x; r[1] = (bf16)a.y; r[2] = (bf16)a.z; r[3] = (bf16)a.w;
    r[4] = (bf16)b.x; r[5] = (bf16)b.y; r[6] = (bf16)b.z; r[7] = (bf16)b.w;
    *(bf16x8*)dst = r;
  } else {
    const int c = tid;                            // w7t[tap*256+c] = w7[c*49+tap]
    #pragma unroll
    for (int tap = 0; tap < 49; tap++)
      w7t[tap * 256 + c] = w7[c * 49 + tap];
  }
}

// ---------------------------------------------------------------------------
// 1) dwconv 7x7 s4 p3 + BN1 + exact GELU + per-ch scale + BN2 -> kv1 (bf16)
//    branch-free: all 26 loads issued before any use (register arrays force
//    pipelining; a 12-VGPR body serializes 13 HBM latencies — r5 lesson).
// ---------------------------------------------------------------------------
__global__ __launch_bounds__(256) void k_sr(
    const float* __restrict__ x, const float* __restrict__ w7t,
    const float* __restrict__ g1, const float* __restrict__ b1,
    const float* __restrict__ m1, const float* __restrict__ v1,
    const float* __restrict__ sw2,
    const float* __restrict__ g2, const float* __restrict__ b2,
    const float* __restrict__ m2, const float* __restrict__ v2,
    bf16* __restrict__ kv1) {
  __shared__ float part[4][256];
  const int tid = threadIdx.x;
  const int team = tid >> 6, g = tid & 63;     // team = wave
  const int c0 = g * 4;
  const int blk = blockIdx.x;
  const int b = blk & 7, m = blk >> 3;
  const int oy = m >> 4, ox = m & 15;

  float4 xv[13], wv[13];
  float msk[13];
  #pragma unroll
  for (int j = 0; j < 13; j++) {               // issue ALL loads first
    const int tap = team + j * 4;
    const int ky = tap / 7, kx = tap - ky * 7;
    const int iy = oy * 4 - 3 + ky, ix = ox * 4 - 3 + kx;
    msk[j] = (tap < 49 && iy >= 0 && iy < 64 && ix >= 0 && ix < 64) ? 1.f : 0.f;
    const int iyc = iy < 0 ? 0 : (iy > 63 ? 63 : iy);
    const int ixc = ix < 0 ? 0 : (ix > 63 ? 63 : ix);
    const int tc = tap > 48 ? 48 : tap;
    xv[j] = *(const float4*)(x + ((size_t)b * 4096 + iyc * 64 + ixc) * 256 + c0);
    wv[j] = *(const float4*)(w7t + tc * 256 + c0);
  }
  float a0 = 0.f, a1 = 0.f, a2 = 0.f, a3 = 0.f;
  #pragma unroll
  for (int j = 0; j < 13; j++) {
    a0 += xv[j].x * wv[j].x * msk[j];
    a1 += xv[j].y * wv[j].y * msk[j];
    a2 += xv[j].z * wv[j].z * msk[j];
    a3 += xv[j].w * wv[j].w * msk[j];
  }
  *(f32x4*)&part[team][c0] = (f32x4){a0, a1, a2, a3};
  __syncthreads();
  const int c = tid;
  float y = part[0][c] + part[1][c] + part[2][c] + part[3][c];
  float s = g1[c] / sqrtf(v1[c] + 1e-5f);
  y = y * s + (b1[c] - m1[c] * s);
  y = 0.5f * y * (1.f + erff(y * 0.70710678118654752f));   // exact GELU
  y *= sw2[c];
  s = g2[c] / sqrtf(v2[c] + 1e-5f);
  y = y * s + (b2[c] - m2[c] * s);
  kv1[((size_t)b * 256 + m) * 256 + c] = (bf16)y;
}

// ---------------------------------------------------------------------------
// 2) FUSED local dw3x3(+bias+residual) + KV projection.
//    grid (32, B): block = 8 pixels. Halo in LDS -> conv -> fp32 rows -> GEMV.
//    dd<256 -> K (bh, m, hd) bf16; dd>=256 -> V^T (bh, hd, m)
// ---------------------------------------------------------------------------
__global__ __launch_bounds__(256) void k_localkv(
    const bf16* __restrict__ kv1, const float* __restrict__ w3,
    const float* __restrict__ lb, const bf16* __restrict__ Wkvb,
    const float* __restrict__ bkv, bf16* __restrict__ k_a,
    bf16* __restrict__ v_b) {
  __shared__ bf16 halo[3][10][256];
  __shared__ float rows[8][256];
  const int c = threadIdx.x;
  const int mt = blockIdx.x;   // 32 tiles of 8 pixels
  const int b = blockIdx.y;
  const int oy = mt >> 1, o0 = (mt & 1) * 8;

  #pragma unroll
  for (int p = 0; p < 30; p++) {
    const int dy = p / 10, xi = p - dy * 10;
    const int iy = oy - 1 + dy, ix = o0 - 1 + xi;
    const bool ok = (iy >= 0 && iy < 16 && ix >= 0 && ix < 16);
    const int iyc = ok ? iy : 0, ixc = ok ? ix : 0;
    const bf16 v = kv1[((size_t)b * 256 + iyc * 16 + ixc) * 256 + c];
    halo[dy][xi][c] = ok ? v : (bf16)0.f;
  }
  float w3f[9];
  #pragma unroll
  for (int t = 0; t < 9; t++) w3f[t] = w3[c * 9 + t];
  const float lbf = lb[c];
  __syncthreads();

  #pragma unroll
  for (int r = 0; r < 8; r++) {
    float acc = lbf + (float)halo[1][r + 1][c];   // bias + residual center
    #pragma unroll
    for (int ky = 0; ky < 3; ky++)
      #pragma unroll
      for (int kx = 0; kx < 3; kx++)
        acc += (float)halo[ky][r + kx][c] * w3f[ky * 3 + kx];
    rows[r][c] = acc;
  }
  __syncthreads();

  const int tid = c;
  float acck[8] = {0}, accv[8] = {0};
  for (int oc = 0; oc < 32; oc++) {
    const bf16x8 w0 = *(const bf16x8*)(Wkvb + (size_t)tid * 256 + oc * 8);
    const bf16x8 w1 = *(const bf16x8*)(Wkvb + ((size_t)tid + 256) * 256 + oc * 8);
    float wf0[8], wf1[8];
    #pragma unroll
    for (int j = 0; j < 8; j++) { wf0[j] = (float)w0[j]; wf1[j] = (float)w1[j]; }
    #pragma unroll
    for (int r = 0; r < 8; r++) {
      const float4* rp = (const float4*)&rows[r][oc * 8];
      const float4 ra = rp[0], rb = rp[1];
      const float rv[8] = {ra.x, ra.y, ra.z, ra.w, rb.x, rb.y, rb.z, rb.w};
      #pragma unroll
      for (int j = 0; j < 8; j++) {
        acck[r] += wf0[j] * rv[j];
        accv[r] += wf1[j] * rv[j];
      }
    }
  }
  const float bk = bkv[tid], bv = bkv[tid + 256];
  const int h = tid >> 5, d = tid & 31;
  #pragma unroll
  for (int r = 0; r < 8; r++) {
    const int m = (oy * 16 + o0) + r;
    k_a[(((size_t)b * 8 + h) * 256 + m) * 32 + d] = (bf16)(acck[r] + bk);
    v_b[(((size_t)b * 8 + h) * 32 + d) * 256 + m] = (bf16)(accv[r] + bv);
  }
}

// ---------------------------------------------------------------------------
// 3) FUSED q-projection + attention, v2.
//    grid (64, 2, B), 256 thr = 4 waves. Block = 64 queries, 4 heads
//    (head = blockIdx.y*4 + wave). Projection is duplicated across
//    blockIdx.y (trivial MFMA cost, x reads are L3-resident) to get back
//    to 1024 blocks / 4096 attention waves = the old k_attn occupancy.
//    Attention wave loop is instruction-identical to the verified r7
//    k_attn: wave = 64 queries x 1 head, 4 query tiles amortize each K/V
//    chunk load (16 MFMA per 64 B/lane), explicit next-chunk prefetch.
// ---------------------------------------------------------------------------
__global__ __launch_bounds__(256) void k_qattn(
    const float* __restrict__ x, const bf16* __restrict__ Wqb,
    const float* __restrict__ bq, const bf16* __restrict__ k_a,
    const bf16* __restrict__ v_b, float* __restrict__ out) {
  __shared__ bf16 qx[64 * 264];   // 264-elem row stride (528 B)
  const int tid = threadIdx.x, wv = tid >> 6, lane = tid & 63;
  const int qd = lane >> 4, l15 = lane & 15;
  const int b = blockIdx.z;
  const int n0 = blockIdx.x * 64;

  // ---- stage x (64 rows x 256 ch fp32) as bf16 into LDS ----
  #pragma unroll
  for (int it = 0; it < 8; it++) {
    const int idx = it * 256 + tid;
    const int lr = idx >> 5, pos = idx & 31;     // pos = 8-ch piece within row
    const float* src = x + ((size_t)b * 4096 + n0 + lr) * 256 + pos * 8;
    const float4 a = ((const float4*)src)[0];
    const float4 bb = ((const float4*)src)[1];
    bf16x8 r;
    r[0] = (bf16)a.x;  r[1] = (bf16)a.y;  r[2] = (bf16)a.z;  r[3] = (bf16)a.w;
    r[4] = (bf16)bb.x; r[5] = (bf16)bb.y; r[6] = (bf16)bb.z; r[7] = (bf16)bb.w;
    *(bf16x8*)(qx + lr * 264 + pos * 8) = r;
  }
  __syncthreads();

  // ---- phase 1: q projection, wave = 16 rows x 256 cols ----
  bf16x8 af[8];
  #pragma unroll
  for (int kc = 0; kc < 8; kc++)
    af[kc] = *(const bf16x8*)(qx + (wv * 16 + l15) * 264 + kc * 32 + qd * 8);

  f32x4 acc[16];
  #pragma unroll
  for (int dt = 0; dt < 16; dt++) acc[dt] = (f32x4){0.f, 0.f, 0.f, 0.f};
  #pragma unroll
  for (int dt = 0; dt < 16; dt++) {
    #pragma unroll
    for (int kc = 0; kc < 8; kc++) {
      const bf16x8 bb =
          *(const bf16x8*)(Wqb + (size_t)(dt * 16 + l15) * 256 + kc * 32 + qd * 8);
      acc[dt] = mfma16(af[kc], bb, acc[dt]);
    }
  }
  __syncthreads();   // af reads done; qx rows about to be overwritten with q
  // D layout: col=l15 -> channel d, row=qd*4+r -> query row (verified layout)
  #pragma unroll
  for (int dt = 0; dt < 16; dt++) {
    const int d = dt * 16 + l15;
    const float bias = bq[d];
    #pragma unroll
    for (int r = 0; r < 4; r++) {
      const int row = wv * 16 + qd * 4 + r;
      qx[row * 264 + d] = (bf16)((acc[dt][r] + bias) * QSCALE);
    }
  }
  __syncthreads();   // q is read cross-wave below

  // ---- phase 2: attention, wave = 64 queries x 1 head (old k_attn loop) ----
  const int h = blockIdx.y * 4 + wv;
  const int bh = b * 8 + h;
  const bf16* kb = k_a + (size_t)bh * 256 * 32;
  const bf16* vb = v_b + (size_t)bh * 32 * 256;

  // B-operand: lane holds Q[d=qd*8+j][query=l15] for tile qi
  bf16x8 qf[4];
  #pragma unroll
  for (int qi = 0; qi < 4; qi++)
    qf[qi] = *(const bf16x8*)(qx + (qi * 16 + l15) * 264 + h * 32 + qd * 8);

  f32x4 oacc[4][2];
  float lr[4] = {0.f, 0.f, 0.f, 0.f};
  #pragma unroll
  for (int qi = 0; qi < 4; qi++) {
    oacc[qi][0] = (f32x4){0.f, 0.f, 0.f, 0.f};
    oacc[qi][1] = (f32x4){0.f, 0.f, 0.f, 0.f};
  }
  // permuted key row: A-tile t row l15 holds key 8*(l15>>2) + 4*t + (l15&3)
  const int kperm = 8 * (l15 >> 2) + (l15 & 3);

  bf16x8 ka0 = *(const bf16x8*)(kb + (size_t)kperm * 32 + qd * 8);
  bf16x8 ka1 = *(const bf16x8*)(kb + (size_t)(kperm + 4) * 32 + qd * 8);
  bf16x8 va0 = *(const bf16x8*)(vb + (size_t)l15 * 256 + qd * 8);
  bf16x8 va1 = *(const bf16x8*)(vb + (size_t)(16 + l15) * 256 + qd * 8);

  for (int ch = 0; ch < 8; ch++) {               // 8 chunks x 32 keys
    const int cn = (ch < 7 ? ch + 1 : 7) * 32;   // prefetch next (clamped)
    const bf16x8 nk0 = *(const bf16x8*)(kb + (size_t)(cn + kperm) * 32 + qd * 8);
    const bf16x8 nk1 = *(const bf16x8*)(kb + (size_t)(cn + kperm + 4) * 32 + qd * 8);
    const bf16x8 nv0 = *(const bf16x8*)(vb + (size_t)l15 * 256 + cn + qd * 8);
    const bf16x8 nv1 = *(const bf16x8*)(vb + (size_t)(16 + l15) * 256 + cn + qd * 8);
    const f32x4 z = (f32x4){0.f, 0.f, 0.f, 0.f};
    #pragma unroll
    for (int qi = 0; qi < 4; qi++) {
      // lane: scores for keys ch*32 + 8*qd + {0..3} (s0), +4+{0..3} (s1)
      f32x4 s0 = mfma16(ka0, qf[qi], z);
      f32x4 s1 = mfma16(ka1, qf[qi], z);
      float p[8], ls = 0.f;
      #pragma unroll
      for (int j = 0; j < 4; j++) {
        p[j] = __builtin_amdgcn_exp2f(fminf(s0[j], 80.f));
        p[4 + j] = __builtin_amdgcn_exp2f(fminf(s1[j], 80.f));
      }
      #pragma unroll
      for (int j = 0; j < 8; j++) ls += p[j];
      lr[qi] += ls;
      bf16x8 pb;                      // B-operand: k = qd*8+j == key-in-chunk
      #pragma unroll
      for (int j = 0; j < 8; j++) pb[j] = (bf16)p[j];
      oacc[qi][0] = mfma16(va0, pb, oacc[qi][0]);
      oacc[qi][1] = mfma16(va1, pb, oacc[qi][1]);
    }
    ka0 = nk0; ka1 = nk1; va0 = nv0; va1 = nv1;
  }
  #pragma unroll
  for (int qi = 0; qi < 4; qi++) {
    float l = lr[qi];
    l += __shfl_xor(l, 16, 64);
    l += __shfl_xor(l, 32, 64);
    const float inv = 1.f / l;
    const int nn = n0 + qi * 16 + l15;
    float* ob = out + (size_t)(b * 4096 + nn) * 256 + h * 32;
    #pragma unroll
    for (int t = 0; t < 2; t++) {
      *(float4*)(ob + t * 16 + qd * 4) =
          (float4){oacc[qi][t][0] * inv, oacc[qi][t][1] * inv,
                   oacc[qi][t][2] * inv, oacc[qi][t][3] * inv};
    }
  }
}

// ---------------------------------------------------------------------------
extern "C" void kernel_launch(void* const* d_in, const int* in_sizes, int n_in,
                              void* d_out, int out_size, void* d_ws, size_t ws_size,
                              hipStream_t stream) {
  const float* x      = (const float*)d_in[0];
  // d_in[1]=h, d_in[2]=w (64, 64) — compile-time constants here
  const float* Wq     = (const float*)d_in[3];
  const float* bq     = (const float*)d_in[4];
  const float* Wkv    = (const float*)d_in[5];
  const float* bkv    = (const float*)d_in[6];
  const float* sr_w1  = (const float*)d_in[7];
  const float* bn1_g  = (const float*)d_in[8];
  const float* bn1_b  = (const float*)d_in[9];
  const float* bn1_m  = (const float*)d_in[10];
  const float* bn1_v  = (const float*)d_in[11];
  const float* sw2    = (const float*)d_in[12];
  const float* bn2_g  = (const float*)d_in[13];
  const float* bn2_b  = (const float*)d_in[14];
  const float* bn2_m  = (const float*)d_in[15];
  const float* bn2_v  = (const float*)d_in[16];
  const float* lw     = (const float*)d_in[17];
  const float* lb     = (const float*)d_in[18];

  const int B = in_sizes[0] / (4096 * 256);   // = 8

  // workspace (~3 MB; d_ws is 256 MB per harness fill size):
  bf16* Wqb  = (bf16*)d_ws;                        // 65536 elems
  bf16* Wkvb = Wqb + 65536;                        // 131072 elems
  float* w7t = (float*)(Wkvb + 131072);            // 49*256 fp32
  bf16* kv1  = (bf16*)(w7t + 12544);               // (B,256,256)
  bf16* k_a  = kv1 + (size_t)B * 256 * 256;        // (bh,256,32)
  bf16* v_b  = k_a + (size_t)B * 8 * 256 * 32;     // (bh,32,256)

  k_cvt<<<dim3(97), 256, 0, stream>>>(Wq, Wkv, sr_w1, Wqb, Wkvb, w7t);
  k_sr<<<dim3(256 * B), 256, 0, stream>>>(x, w7t, bn1_g, bn1_b, bn1_m, bn1_v,
                                          sw2, bn2_g, bn2_b, bn2_m, bn2_v, kv1);
  k_localkv<<<dim3(32, B), 256, 0, stream>>>(kv1, lw, lb, Wkvb, bkv, k_a, v_b);
  k_qattn<<<dim3(64, 2, B), 256, 0, stream>>>(x, Wqb, bq, k_a, v_b,
                                              (float*)d_out);
}

// Round 3
// 183.902 us; speedup vs baseline: 1.2921x; 1.2921x over previous
//
#include <hip/hip_runtime.h>
#include <math.h>

typedef __bf16 bf16;
typedef bf16 bf16x4 __attribute__((ext_vector_type(4)));
typedef bf16 bf16x8 __attribute__((ext_vector_type(8)));
typedef float f32x4 __attribute__((ext_vector_type(4)));

static_assert(sizeof(bf16x8) == 16, "bf16x8 must be 16B");

// q pre-scale: (1/sqrt(hd=32)) * log2(e)  -> softmax via exp2
#define QSCALE (0.17677669529663687f * 1.4426950408889634f)

__device__ __forceinline__ f32x4 mfma16(bf16x8 a, bf16x8 b, f32x4 c) {
  return __builtin_amdgcn_mfma_f32_16x16x32_bf16(a, b, c, 0, 0, 0);
}

// ---------------------------------------------------------------------------
// 0) weight prep: Wq->bf16, Wkv->bf16, w7 -> transposed fp32 w7t[tap][c]
//    grid = 32 (Wq) + 64 (Wkv) + 1 (w7t) = 97 blocks
// ---------------------------------------------------------------------------
__global__ __launch_bounds__(256) void k_cvt(
    const float* __restrict__ Wq, const float* __restrict__ Wkv,
    const float* __restrict__ w7, bf16* __restrict__ Wqb,
    bf16* __restrict__ Wkvb, float* __restrict__ w7t) {
  const int tid = threadIdx.x;
  const int blk = blockIdx.x;
  if (blk < 96) {
    const float* src;
    bf16* dst;
    if (blk < 32) {
      const int idx = blk * 256 + tid;            // Wq: 65536/8 = 8192
      src = Wq + (size_t)idx * 8;
      dst = Wqb + (size_t)idx * 8;
    } else {
      const int idx = (blk - 32) * 256 + tid;     // Wkv: 131072/8 = 16384
      src = Wkv + (size_t)idx * 8;
      dst = Wkvb + (size_t)idx * 8;
    }
    const float4 a = ((const float4*)src)[0];
    const float4 b = ((const float4*)src)[1];
    bf16x8 r;
    r[0] = (bf16)a.x; r[1] = (bf16)a.y; r[2] = (bf16)a.z; r[3] = (bf16)a.w;
    r[4] = (bf16)b.x; r[5] = (bf16)b.y; r[6] = (bf16)b.z; r[7] = (bf16)b.w;
    *(bf16x8*)dst = r;
  } else {
    const int c = tid;                            // w7t[tap*256+c] = w7[c*49+tap]
    #pragma unroll
    for (int tap = 0; tap < 49; tap++)
      w7t[tap * 256 + c] = w7[c * 49 + tap];
  }
}

// ---------------------------------------------------------------------------
// 1) dwconv 7x7 s4 p3 + BN1 + exact GELU + per-ch scale + BN2 -> kv1 (bf16)
//    branch-free: all 26 loads issued before any use (register arrays force
//    pipelining; a 12-VGPR body serializes 13 HBM latencies — r5 lesson).
// ---------------------------------------------------------------------------
__global__ __launch_bounds__(256) void k_sr(
    const float* __restrict__ x, const float* __restrict__ w7t,
    const float* __restrict__ g1, const float* __restrict__ b1,
    const float* __restrict__ m1, const float* __restrict__ v1,
    const float* __restrict__ sw2,
    const float* __restrict__ g2, const float* __restrict__ b2,
    const float* __restrict__ m2, const float* __restrict__ v2,
    bf16* __restrict__ kv1) {
  __shared__ float part[4][256];
  const int tid = threadIdx.x;
  const int team = tid >> 6, g = tid & 63;     // team = wave
  const int c0 = g * 4;
  const int blk = blockIdx.x;
  const int b = blk & 7, m = blk >> 3;
  const int oy = m >> 4, ox = m & 15;

  float4 xv[13], wv[13];
  float msk[13];
  #pragma unroll
  for (int j = 0; j < 13; j++) {               // issue ALL loads first
    const int tap = team + j * 4;
    const int ky = tap / 7, kx = tap - ky * 7;
    const int iy = oy * 4 - 3 + ky, ix = ox * 4 - 3 + kx;
    msk[j] = (tap < 49 && iy >= 0 && iy < 64 && ix >= 0 && ix < 64) ? 1.f : 0.f;
    const int iyc = iy < 0 ? 0 : (iy > 63 ? 63 : iy);
    const int ixc = ix < 0 ? 0 : (ix > 63 ? 63 : ix);
    const int tc = tap > 48 ? 48 : tap;
    xv[j] = *(const float4*)(x + ((size_t)b * 4096 + iyc * 64 + ixc) * 256 + c0);
    wv[j] = *(const float4*)(w7t + tc * 256 + c0);
  }
  float a0 = 0.f, a1 = 0.f, a2 = 0.f, a3 = 0.f;
  #pragma unroll
  for (int j = 0; j < 13; j++) {
    a0 += xv[j].x * wv[j].x * msk[j];
    a1 += xv[j].y * wv[j].y * msk[j];
    a2 += xv[j].z * wv[j].z * msk[j];
    a3 += xv[j].w * wv[j].w * msk[j];
  }
  *(f32x4*)&part[team][c0] = (f32x4){a0, a1, a2, a3};
  __syncthreads();
  const int c = tid;
  float y = part[0][c] + part[1][c] + part[2][c] + part[3][c];
  float s = g1[c] / sqrtf(v1[c] + 1e-5f);
  y = y * s + (b1[c] - m1[c] * s);
  y = 0.5f * y * (1.f + erff(y * 0.70710678118654752f));   // exact GELU
  y *= sw2[c];
  s = g2[c] / sqrtf(v2[c] + 1e-5f);
  y = y * s + (b2[c] - m2[c] * s);
  kv1[((size_t)b * 256 + m) * 256 + c] = (bf16)y;
}

// ---------------------------------------------------------------------------
// 2) FUSED local dw3x3(+bias+residual) + KV projection, v2: K/V block split.
//    grid (32, 2, B): blockIdx.y==0 computes the K half (dd = tid),
//    blockIdx.y==1 computes the V half (dd = tid + 256). The halo+conv is
//    duplicated across the pair (cheap, kv1 is L2-resident) but the serial
//    GEMV tail — the occupancy-starved part (was 256 blocks = 1 wave/SIMD)
//    — halves per block and runs on 2x the CUs. Arithmetic order per output
//    element is unchanged -> bit-identical results.
// ---------------------------------------------------------------------------
__global__ __launch_bounds__(256) void k_localkv(
    const bf16* __restrict__ kv1, const float* __restrict__ w3,
    const float* __restrict__ lb, const bf16* __restrict__ Wkvb,
    const float* __restrict__ bkv, bf16* __restrict__ k_a,
    bf16* __restrict__ v_b) {
  __shared__ bf16 halo[3][10][256];
  __shared__ float rows[8][256];
  const int c = threadIdx.x;
  const int mt = blockIdx.x;   // 32 tiles of 8 pixels
  const int part = blockIdx.y; // 0 = K half, 1 = V half
  const int b = blockIdx.z;
  const int oy = mt >> 1, o0 = (mt & 1) * 8;

  #pragma unroll
  for (int p = 0; p < 30; p++) {
    const int dy = p / 10, xi = p - dy * 10;
    const int iy = oy - 1 + dy, ix = o0 - 1 + xi;
    const bool ok = (iy >= 0 && iy < 16 && ix >= 0 && ix < 16);
    const int iyc = ok ? iy : 0, ixc = ok ? ix : 0;
    const bf16 v = kv1[((size_t)b * 256 + iyc * 16 + ixc) * 256 + c];
    halo[dy][xi][c] = ok ? v : (bf16)0.f;
  }
  float w3f[9];
  #pragma unroll
  for (int t = 0; t < 9; t++) w3f[t] = w3[c * 9 + t];
  const float lbf = lb[c];
  __syncthreads();

  #pragma unroll
  for (int r = 0; r < 8; r++) {
    float acc = lbf + (float)halo[1][r + 1][c];   // bias + residual center
    #pragma unroll
    for (int ky = 0; ky < 3; ky++)
      #pragma unroll
      for (int kx = 0; kx < 3; kx++)
        acc += (float)halo[ky][r + kx][c] * w3f[ky * 3 + kx];
    rows[r][c] = acc;
  }
  __syncthreads();

  const int tid = c;
  const size_t wrow = (size_t)tid + (part ? 256 : 0);
  float accs[8] = {0};
  for (int oc = 0; oc < 32; oc++) {
    const bf16x8 w0 = *(const bf16x8*)(Wkvb + wrow * 256 + oc * 8);
    float wf0[8];
    #pragma unroll
    for (int j = 0; j < 8; j++) wf0[j] = (float)w0[j];
    #pragma unroll
    for (int r = 0; r < 8; r++) {
      const float4* rp = (const float4*)&rows[r][oc * 8];
      const float4 ra = rp[0], rb = rp[1];
      const float rv[8] = {ra.x, ra.y, ra.z, ra.w, rb.x, rb.y, rb.z, rb.w};
      #pragma unroll
      for (int j = 0; j < 8; j++) accs[r] += wf0[j] * rv[j];
    }
  }
  const float bias = bkv[wrow];
  const int h = tid >> 5, d = tid & 31;
  if (part == 0) {
    #pragma unroll
    for (int r = 0; r < 8; r++) {
      const int m = (oy * 16 + o0) + r;
      k_a[(((size_t)b * 8 + h) * 256 + m) * 32 + d] = (bf16)(accs[r] + bias);
    }
  } else {
    #pragma unroll
    for (int r = 0; r < 8; r++) {
      const int m = (oy * 16 + o0) + r;
      v_b[(((size_t)b * 8 + h) * 32 + d) * 256 + m] = (bf16)(accs[r] + bias);
    }
  }
}

// ---------------------------------------------------------------------------
// 3) Q projection (MFMA). Block = 32 rows, wave = 32 rows x 64 cols
//    (every B-frag feeds 2 MFMAs). q bf16 -> q_ws (bh, n, 32) contiguous.
// ---------------------------------------------------------------------------
__global__ __launch_bounds__(256) void k_qproj(
    const float* __restrict__ x, const bf16* __restrict__ Wqb,
    const float* __restrict__ bq, bf16* __restrict__ q_ws) {
  __shared__ bf16 xs[32 * 264];                // 264 elems = 528 B row stride
  const int tid = threadIdx.x, wv = tid >> 6, lane = tid & 63;
  const int qd = lane >> 4, l15 = lane & 15;
  const size_t rowbase = (size_t)blockIdx.x * 32;

  #pragma unroll
  for (int it = 0; it < 4; it++) {             // stage 32 rows x 256 ch fp32
    const int idx = it * 256 + tid;
    const int lr = idx >> 5, pos = idx & 31;   // pos = 8-ch piece within row
    const float* src = x + (rowbase + lr) * 256 + pos * 8;
    const float4 a = ((const float4*)src)[0];
    const float4 b = ((const float4*)src)[1];
    bf16x8 r;
    r[0] = (bf16)a.x; r[1] = (bf16)a.y; r[2] = (bf16)a.z; r[3] = (bf16)a.w;
    r[4] = (bf16)b.x; r[5] = (bf16)b.y; r[6] = (bf16)b.z; r[7] = (bf16)b.w;
    *(bf16x8*)(xs + lr * 264 + pos * 8) = r;
  }
  __syncthreads();

  f32x4 acc0[4], acc1[4];
  #pragma unroll
  for (int dt = 0; dt < 4; dt++) {
    acc0[dt] = (f32x4){0.f, 0.f, 0.f, 0.f};
    acc1[dt] = (f32x4){0.f, 0.f, 0.f, 0.f};
  }
  #pragma unroll 2
  for (int kc = 0; kc < 8; kc++) {
    const bf16x8 a0 = *(const bf16x8*)(xs + l15 * 264 + kc * 32 + qd * 8);
    const bf16x8 a1 = *(const bf16x8*)(xs + (16 + l15) * 264 + kc * 32 + qd * 8);
    #pragma unroll
    for (int dt = 0; dt < 4; dt++) {
      const int d = wv * 64 + dt * 16 + l15;
      const bf16x8 bb = *(const bf16x8*)(Wqb + (size_t)d * 256 + kc * 32 + qd * 8);
      acc0[dt] = mfma16(a0, bb, acc0[dt]);
      acc1[dt] = mfma16(a1, bb, acc1[dt]);
    }
  }
  #pragma unroll
  for (int dt = 0; dt < 4; dt++) {
    const int d = wv * 64 + dt * 16 + l15;        // D col = l15 -> channel d
    const float bias = bq[d];
    const int h = d >> 5, dl = d & 31;
    #pragma unroll
    for (int r = 0; r < 4; r++) {
      const size_t row0 = rowbase + qd * 4 + r;          // global b*4096+nn
      const size_t row1 = rowbase + 16 + qd * 4 + r;
      q_ws[(((row0 >> 12) * 8 + h) * 4096 + (row0 & 4095)) * 32 + dl] =
          (bf16)((acc0[dt][r] + bias) * QSCALE);
      q_ws[(((row1 >> 12) * 8 + h) * 4096 + (row1 & 4095)) * 32 + dl] =
          (bf16)((acc1[dt][r] + bias) * QSCALE);
    }
  }
}

// ---------------------------------------------------------------------------
// 4) attention, NO-MAX softmax (shift-invariant; scores |arg| << 80, clamp is
//    a pure overflow guard). Per (b,h): S^T = K.Q^T, p = exp2(s), O^T = V^T.P^T,
//    normalize by sum at the end. No shuffles / alpha / rescale in the loop —
//    the r7 profile showed that chain (VALUBusy 40%, MfmaUtil 7%) was the cost.
//    grid (16, 8, B), 256 thr; wave = 64 queries (4 tiles of 16).
//    K rows permuted at load so P lands directly in B-operand layout.
// ---------------------------------------------------------------------------
__global__ __launch_bounds__(256) void k_attn(
    const bf16* __restrict__ q_ws, const bf16* __restrict__ k_a,
    const bf16* __restrict__ v_b, float* __restrict__ out) {
  const int tid = threadIdx.x;
  const int wv = tid >> 6, lane = tid & 63;
  const int qd = lane >> 4, l15 = lane & 15;
  const int b = blockIdx.z, h = blockIdx.y;
  const int bh = b * 8 + h;
  const int n_base = blockIdx.x * 256 + wv * 64;

  const bf16* qb = q_ws + ((size_t)bh * 4096 + n_base) * 32;
  bf16x8 qf[4];   // B-operand: lane holds Q[d=qd*8+j][query=l15]
  #pragma unroll
  for (int qi = 0; qi < 4; qi++)
    qf[qi] = *(const bf16x8*)(qb + (size_t)(qi * 16 + l15) * 32 + qd * 8);

  const bf16* kb = k_a + (size_t)bh * 256 * 32;
  const bf16* vb = v_b + (size_t)bh * 32 * 256;

  f32x4 acc[4][2];
  float lr[4] = {0.f, 0.f, 0.f, 0.f};
  #pragma unroll
  for (int qi = 0; qi < 4; qi++) {
    acc[qi][0] = (f32x4){0.f, 0.f, 0.f, 0.f};
    acc[qi][1] = (f32x4){0.f, 0.f, 0.f, 0.f};
  }
  // permuted key row: A-tile t row l15 holds key 8*(l15>>2) + 4*t + (l15&3)
  const int kperm = 8 * (l15 >> 2) + (l15 & 3);

  bf16x8 ka0 = *(const bf16x8*)(kb + (size_t)kperm * 32 + qd * 8);
  bf16x8 ka1 = *(const bf16x8*)(kb + (size_t)(kperm + 4) * 32 + qd * 8);
  bf16x8 va0 = *(const bf16x8*)(vb + (size_t)l15 * 256 + qd * 8);
  bf16x8 va1 = *(const bf16x8*)(vb + (size_t)(16 + l15) * 256 + qd * 8);

  for (int ch = 0; ch < 8; ch++) {               // 8 chunks x 32 keys
    const int cn = (ch < 7 ? ch + 1 : 7) * 32;   // prefetch next (clamped)
    const bf16x8 nk0 = *(const bf16x8*)(kb + (size_t)(cn + kperm) * 32 + qd * 8);
    const bf16x8 nk1 = *(const bf16x8*)(kb + (size_t)(cn + kperm + 4) * 32 + qd * 8);
    const bf16x8 nv0 = *(const bf16x8*)(vb + (size_t)l15 * 256 + cn + qd * 8);
    const bf16x8 nv1 = *(const bf16x8*)(vb + (size_t)(16 + l15) * 256 + cn + qd * 8);
    const f32x4 z = (f32x4){0.f, 0.f, 0.f, 0.f};
    #pragma unroll
    for (int qi = 0; qi < 4; qi++) {
      // lane: scores for keys ch*32 + 8*qd + {0..3} (s0), +4+{0..3} (s1)
      f32x4 s0 = mfma16(ka0, qf[qi], z);
      f32x4 s1 = mfma16(ka1, qf[qi], z);
      float p[8], ls = 0.f;
      #pragma unroll
      for (int j = 0; j < 4; j++) {
        p[j] = __builtin_amdgcn_exp2f(fminf(s0[j], 80.f));
        p[4 + j] = __builtin_amdgcn_exp2f(fminf(s1[j], 80.f));
      }
      #pragma unroll
      for (int j = 0; j < 8; j++) ls += p[j];
      lr[qi] += ls;
      bf16x8 pb;                      // B-operand: k = qd*8+j == key-in-chunk
      #pragma unroll
      for (int j = 0; j < 8; j++) pb[j] = (bf16)p[j];
      acc[qi][0] = mfma16(va0, pb, acc[qi][0]);
      acc[qi][1] = mfma16(va1, pb, acc[qi][1]);
    }
    ka0 = nk0; ka1 = nk1; va0 = nv0; va1 = nv1;
  }
  #pragma unroll
  for (int qi = 0; qi < 4; qi++) {
    float l = lr[qi];
    l += __shfl_xor(l, 16, 64);
    l += __shfl_xor(l, 32, 64);
    const float inv = 1.f / l;
    const int nn = n_base + qi * 16 + l15;
    float* ob = out + (size_t)(b * 4096 + nn) * 256 + h * 32;
    #pragma unroll
    for (int t = 0; t < 2; t++) {
      *(float4*)(ob + t * 16 + qd * 4) =
          (float4){acc[qi][t][0] * inv, acc[qi][t][1] * inv,
                   acc[qi][t][2] * inv, acc[qi][t][3] * inv};
    }
  }
}

// ---------------------------------------------------------------------------
extern "C" void kernel_launch(void* const* d_in, const int* in_sizes, int n_in,
                              void* d_out, int out_size, void* d_ws, size_t ws_size,
                              hipStream_t stream) {
  const float* x      = (const float*)d_in[0];
  // d_in[1]=h, d_in[2]=w (64, 64) — compile-time constants here
  const float* Wq     = (const float*)d_in[3];
  const float* bq     = (const float*)d_in[4];
  const float* Wkv    = (const float*)d_in[5];
  const float* bkv    = (const float*)d_in[6];
  const float* sr_w1  = (const float*)d_in[7];
  const float* bn1_g  = (const float*)d_in[8];
  const float* bn1_b  = (const float*)d_in[9];
  const float* bn1_m  = (const float*)d_in[10];
  const float* bn1_v  = (const float*)d_in[11];
  const float* sw2    = (const float*)d_in[12];
  const float* bn2_g  = (const float*)d_in[13];
  const float* bn2_b  = (const float*)d_in[14];
  const float* bn2_m  = (const float*)d_in[15];
  const float* bn2_v  = (const float*)d_in[16];
  const float* lw     = (const float*)d_in[17];
  const float* lb     = (const float*)d_in[18];

  const int B = in_sizes[0] / (4096 * 256);   // = 8

  // workspace (~20 MB; d_ws is 256 MB per harness fill size):
  bf16* Wqb  = (bf16*)d_ws;                        // 65536 elems
  bf16* Wkvb = Wqb + 65536;                        // 131072 elems
  float* w7t = (float*)(Wkvb + 131072);            // 49*256 fp32
  bf16* kv1  = (bf16*)(w7t + 12544);               // (B,256,256)
  bf16* k_a  = kv1 + (size_t)B * 256 * 256;        // (bh,256,32)
  bf16* v_b  = k_a + (size_t)B * 8 * 256 * 32;     // (bh,32,256)
  bf16* q_ws = v_b + (size_t)B * 8 * 32 * 256;     // (bh,4096,32) 16.8MB

  k_cvt<<<dim3(97), 256, 0, stream>>>(Wq, Wkv, sr_w1, Wqb, Wkvb, w7t);
  k_sr<<<dim3(256 * B), 256, 0, stream>>>(x, w7t, bn1_g, bn1_b, bn1_m, bn1_v,
                                          sw2, bn2_g, bn2_b, bn2_m, bn2_v, kv1);
  k_localkv<<<dim3(32, 2, B), 256, 0, stream>>>(kv1, lw, lb, Wkvb, bkv, k_a, v_b);
  k_qproj<<<dim3(B * 128), 256, 0, stream>>>(x, Wqb, bq, q_ws);
  k_attn<<<dim3(16, 8, B), 256, 0, stream>>>(q_ws, k_a, v_b, (float*)d_out);
}